// Round 2
// baseline (550.125 us; speedup 1.0000x reference)
//
#include <hip/hip_runtime.h>

#define BATCH   16
#define MAXLEN  128
#define VOCAB   32128
#define EMBED   768
#define NROWS   (BATCH * MAXLEN)   // 2048

// ---------------------------------------------------------------------------
// Kernel 1: per-row argmax of (logits + gumbel), then replicate the reference's
// grid_sample-nearest row index transform in bit-exact f32.
// One block (256 threads) per (b,l) row of VOCAB floats.
// ---------------------------------------------------------------------------
__global__ __launch_bounds__(256) void argmax_rows(
        const float* __restrict__ logits,
        const float* __restrict__ gumbel,
        int* __restrict__ row_idx_out) {
    const int row = blockIdx.x;
    const int tid = threadIdx.x;
    const float4* __restrict__ lg = (const float4*)(logits + (size_t)row * VOCAB);
    const float4* __restrict__ gm = (const float4*)(gumbel + (size_t)row * VOCAB);

    float bv = -INFINITY;
    int   bi = 0x7fffffff;
    const int NV4 = VOCAB / 4;              // 8032 float4s, no remainder
    for (int c = tid; c < NV4; c += 256) {
        float4 a = lg[c];
        float4 g = gm[c];
        float v0 = a.x + g.x, v1 = a.y + g.y, v2 = a.z + g.z, v3 = a.w + g.w;
        int base = c * 4;
        // ascending index order + strict '>' keeps the FIRST max (jnp.argmax)
        if (v0 > bv) { bv = v0; bi = base;     }
        if (v1 > bv) { bv = v1; bi = base + 1; }
        if (v2 > bv) { bv = v2; bi = base + 2; }
        if (v3 > bv) { bv = v3; bi = base + 3; }
    }

    // wave (64-lane) reduction, tie-break on lowest index
    for (int off = 32; off > 0; off >>= 1) {
        float ov = __shfl_down(bv, off);
        int   oi = __shfl_down(bi, off);
        if (ov > bv || (ov == bv && oi < bi)) { bv = ov; bi = oi; }
    }
    __shared__ float sv[4];
    __shared__ int   si[4];
    const int wave = tid >> 6;
    if ((tid & 63) == 0) { sv[wave] = bv; si[wave] = bi; }
    __syncthreads();
    if (tid == 0) {
        for (int w = 1; w < 4; ++w)
            if (sv[w] > bv || (sv[w] == bv && si[w] < bi)) { bv = sv[w]; bi = si[w]; }

        // --- replicate: coord = jnp.linspace(-1,1,V)[hot]  (f32, endpoint exact)
        const int hot = bi;
        float coord;
        if (hot == VOCAB - 1) {
            coord = 1.0f;                     // lax.concatenate endpoint
        } else {
            float delta = __fdiv_rn(2.0f, (float)(VOCAB - 1));
            float t     = __fmul_rn((float)hot, delta);
            coord       = __fadd_rn(-1.0f, t);
        }
        // --- replicate _nearest_idx: ((coord+1)*V - 1)/2, round-half-even, clip
        float u  = __fadd_rn(coord, 1.0f);
        float w  = __fmul_rn(u, (float)VOCAB);
        float x  = __fadd_rn(w, -1.0f);
        float ix = __fmul_rn(x, 0.5f);
        float r  = rintf(ix);                 // round-half-to-even (default RN)
        int ri = (int)r;
        ri = ri < 0 ? 0 : (ri > VOCAB - 1 ? VOCAB - 1 : ri);
        row_idx_out[row] = ri;
    }
}

// ---------------------------------------------------------------------------
// Kernel 2: passage branch per batch: shifts, extr, trunc, first-nonzero index.
// One block (128 threads) per batch.
// ---------------------------------------------------------------------------
__global__ __launch_bounds__(128) void prep_psg(
        const int* __restrict__ mask,
        const int* __restrict__ psg,
        int* __restrict__ trunc_out,
        int* __restrict__ firstnz_out) {
    const int b = blockIdx.x;
    const int l = threadIdx.x;
    __shared__ int extr[MAXLEN];
    __shared__ int red[MAXLEN];

    const int m = mask[b * MAXLEN + l];
    red[l] = m;
    __syncthreads();
    for (int s = 64; s > 0; s >>= 1) {
        if (l < s) red[l] += red[l + s];
        __syncthreads();
    }
    const int shift = red[0];                 // = sum(mask[b,:])

    // psg rolled right by 1 with BOS=1; flipped mask
    const int prev = (l == 0) ? 1 : psg[b * MAXLEN + l - 1];
    const int fm   = 1 - mask[b * MAXLEN + (MAXLEN - 1 - l)];
    extr[l] = fm * prev;
    __syncthreads();                          // also protects red[] reuse below

    const int pos = (l - shift + MAXLEN) & (MAXLEN - 1);   // (l-shift) mod 128
    const int tr  = extr[pos];
    trunc_out[b * MAXLEN + l] = tr;

    red[l] = (tr != 0) ? l : MAXLEN;
    __syncthreads();
    for (int s = 64; s > 0; s >>= 1) {
        if (l < s) red[l] = min(red[l], red[l + s]);
        __syncthreads();
    }
    if (l == 0) firstnz_out[b] = red[0];      // flag[l] = (l >= firstnz)
}

// ---------------------------------------------------------------------------
// Kernel 3: out[b,l,:] = (mask ? W[row_idx] : 0) + (flag ? W[trunc] : 0)
// One block (192 threads = 768/4 float4) per (b,l).
// ---------------------------------------------------------------------------
__global__ __launch_bounds__(192) void gather_add(
        const float* __restrict__ W,
        const int* __restrict__ mask,
        const int* __restrict__ row_idx,
        const int* __restrict__ trunc,
        const int* __restrict__ firstnz,
        float* __restrict__ out) {
    const int blk = blockIdx.x;               // b*128 + l
    const int b   = blk >> 7;
    const int l   = blk & (MAXLEN - 1);
    const int tid = threadIdx.x;

    const int m    = mask[blk];
    const int r1   = row_idx[blk];
    const int tr   = trunc[blk];
    const bool flg = (l >= firstnz[b]);

    const float4* __restrict__ W4 = (const float4*)W;
    float4 acc = make_float4(0.f, 0.f, 0.f, 0.f);
    if (m) {                                  // block-uniform branch
        float4 w = W4[(size_t)r1 * (EMBED / 4) + tid];
        acc.x += w.x; acc.y += w.y; acc.z += w.z; acc.w += w.w;
    }
    if (flg) {                                // block-uniform branch
        float4 w = W4[(size_t)tr * (EMBED / 4) + tid];
        acc.x += w.x; acc.y += w.y; acc.z += w.z; acc.w += w.w;
    }
    ((float4*)out)[(size_t)blk * (EMBED / 4) + tid] = acc;
}

// ---------------------------------------------------------------------------
extern "C" void kernel_launch(void* const* d_in, const int* in_sizes, int n_in,
                              void* d_out, int out_size, void* d_ws, size_t ws_size,
                              hipStream_t stream) {
    const float* logits = (const float*)d_in[0];
    const int*   mask   = (const int*)  d_in[1];
    const int*   psg    = (const int*)  d_in[2];
    const float* W      = (const float*)d_in[3];
    const float* gumbel = (const float*)d_in[4];
    float* out = (float*)d_out;

    int* ws_row   = (int*)d_ws;               // [NROWS]
    int* ws_trunc = ws_row + NROWS;           // [NROWS]
    int* ws_fnz   = ws_trunc + NROWS;         // [BATCH]

    argmax_rows<<<NROWS, 256, 0, stream>>>(logits, gumbel, ws_row);
    prep_psg<<<BATCH, MAXLEN, 0, stream>>>(mask, psg, ws_trunc, ws_fnz);
    gather_add<<<NROWS, EMBED / 4, 0, stream>>>(W, mask, ws_row, ws_trunc, ws_fnz, out);
}

// Round 5
// 545.895 us; speedup vs baseline: 1.0077x; 1.0077x over previous
//
#include <hip/hip_runtime.h>

#define BATCH   16
#define MAXLEN  128
#define VOCAB   32128
#define EMBED   768
#define NROWS   (BATCH * MAXLEN)   // 2048
#define NV4     (VOCAB / 4)        // 8032 float4 per row

// ---------------------------------------------------------------------------
// Kernel 1: per-row argmax of (logits + gumbel), 4-way unrolled with
// independent accumulators (8 loads in flight per thread, no cross-chunk
// dependency), then bit-exact replication of the grid_sample-nearest index
// transform. One block (256 threads) per (b,l) row.
// ---------------------------------------------------------------------------
__global__ __launch_bounds__(256) void argmax_rows(
        const float* __restrict__ logits,
        const float* __restrict__ gumbel,
        int* __restrict__ row_idx_out) {
    const int row = blockIdx.x;
    const int tid = threadIdx.x;
    const float4* __restrict__ lg = (const float4*)(logits + (size_t)row * VOCAB);
    const float4* __restrict__ gm = (const float4*)(gumbel + (size_t)row * VOCAB);

    float bv0 = -INFINITY, bv1 = -INFINITY, bv2 = -INFINITY, bv3 = -INFINITY;
    int   bi0 = 0x7fffffff, bi1 = 0x7fffffff, bi2 = 0x7fffffff, bi3 = 0x7fffffff;

    // main: 7 sweeps of 1024 float4s (7168), tail handled below
    const int MAIN = (NV4 / 1024) * 1024;     // 7168
    for (int base = 0; base < MAIN; base += 1024) {
        const int c0 = base + tid;
        const int c1 = c0 + 256;
        const int c2 = c0 + 512;
        const int c3 = c0 + 768;
        float4 a0 = lg[c0], g0 = gm[c0];
        float4 a1 = lg[c1], g1 = gm[c1];
        float4 a2 = lg[c2], g2 = gm[c2];
        float4 a3 = lg[c3], g3 = gm[c3];
        // chunk 0 (indices ascend within each accumulator; strict '>' = first max)
        {
            float v0 = a0.x + g0.x, v1 = a0.y + g0.y, v2 = a0.z + g0.z, v3 = a0.w + g0.w;
            int ib = c0 * 4;
            if (v0 > bv0) { bv0 = v0; bi0 = ib;     }
            if (v1 > bv0) { bv0 = v1; bi0 = ib + 1; }
            if (v2 > bv0) { bv0 = v2; bi0 = ib + 2; }
            if (v3 > bv0) { bv0 = v3; bi0 = ib + 3; }
        }
        {
            float v0 = a1.x + g1.x, v1 = a1.y + g1.y, v2 = a1.z + g1.z, v3 = a1.w + g1.w;
            int ib = c1 * 4;
            if (v0 > bv1) { bv1 = v0; bi1 = ib;     }
            if (v1 > bv1) { bv1 = v1; bi1 = ib + 1; }
            if (v2 > bv1) { bv1 = v2; bi1 = ib + 2; }
            if (v3 > bv1) { bv1 = v3; bi1 = ib + 3; }
        }
        {
            float v0 = a2.x + g2.x, v1 = a2.y + g2.y, v2 = a2.z + g2.z, v3 = a2.w + g2.w;
            int ib = c2 * 4;
            if (v0 > bv2) { bv2 = v0; bi2 = ib;     }
            if (v1 > bv2) { bv2 = v1; bi2 = ib + 1; }
            if (v2 > bv2) { bv2 = v2; bi2 = ib + 2; }
            if (v3 > bv2) { bv2 = v3; bi2 = ib + 3; }
        }
        {
            float v0 = a3.x + g3.x, v1 = a3.y + g3.y, v2 = a3.z + g3.z, v3 = a3.w + g3.w;
            int ib = c3 * 4;
            if (v0 > bv3) { bv3 = v0; bi3 = ib;     }
            if (v1 > bv3) { bv3 = v1; bi3 = ib + 1; }
            if (v2 > bv3) { bv3 = v2; bi3 = ib + 2; }
            if (v3 > bv3) { bv3 = v3; bi3 = ib + 3; }
        }
    }
    // tail: 7168..8031 (864 float4s) on accumulator 0
    for (int c = MAIN + tid; c < NV4; c += 256) {
        float4 a = lg[c], g = gm[c];
        float v0 = a.x + g.x, v1 = a.y + g.y, v2 = a.z + g.z, v3 = a.w + g.w;
        int ib = c * 4;
        if (v0 > bv0) { bv0 = v0; bi0 = ib;     }
        if (v1 > bv0) { bv0 = v1; bi0 = ib + 1; }
        if (v2 > bv0) { bv0 = v2; bi0 = ib + 2; }
        if (v3 > bv0) { bv0 = v3; bi0 = ib + 3; }
    }

    // merge 4 accumulators (equal value -> smaller index, matching first-max)
    float bv = bv0; int bi = bi0;
    if (bv1 > bv || (bv1 == bv && bi1 < bi)) { bv = bv1; bi = bi1; }
    if (bv2 > bv || (bv2 == bv && bi2 < bi)) { bv = bv2; bi = bi2; }
    if (bv3 > bv || (bv3 == bv && bi3 < bi)) { bv = bv3; bi = bi3; }

    // wave (64-lane) reduction, tie-break on lowest index
    for (int off = 32; off > 0; off >>= 1) {
        float ov = __shfl_down(bv, off);
        int   oi = __shfl_down(bi, off);
        if (ov > bv || (ov == bv && oi < bi)) { bv = ov; bi = oi; }
    }
    __shared__ float sv[4];
    __shared__ int   si[4];
    const int wave = tid >> 6;
    if ((tid & 63) == 0) { sv[wave] = bv; si[wave] = bi; }
    __syncthreads();
    if (tid == 0) {
        for (int w = 1; w < 4; ++w)
            if (sv[w] > bv || (sv[w] == bv && si[w] < bi)) { bv = sv[w]; bi = si[w]; }

        // --- replicate: coord = jnp.linspace(-1,1,V)[hot]  (f32, endpoint exact)
        const int hot = bi;
        float coord;
        if (hot == VOCAB - 1) {
            coord = 1.0f;                     // lax.concatenate endpoint
        } else {
            float delta = __fdiv_rn(2.0f, (float)(VOCAB - 1));
            float t     = __fmul_rn((float)hot, delta);
            coord       = __fadd_rn(-1.0f, t);
        }
        // --- replicate _nearest_idx: ((coord+1)*V - 1)/2, round-half-even, clip
        float u  = __fadd_rn(coord, 1.0f);
        float w  = __fmul_rn(u, (float)VOCAB);
        float x  = __fadd_rn(w, -1.0f);
        float ix = __fmul_rn(x, 0.5f);
        float r  = rintf(ix);                 // round-half-to-even (default RN)
        int ri = (int)r;
        ri = ri < 0 ? 0 : (ri > VOCAB - 1 ? VOCAB - 1 : ri);
        row_idx_out[row] = ri;
    }
}

// ---------------------------------------------------------------------------
// Kernel 2: passage branch per batch: shifts, extr, trunc, first-nonzero index.
// One block (128 threads) per batch.
// ---------------------------------------------------------------------------
__global__ __launch_bounds__(128) void prep_psg(
        const int* __restrict__ mask,
        const int* __restrict__ psg,
        int* __restrict__ trunc_out,
        int* __restrict__ firstnz_out) {
    const int b = blockIdx.x;
    const int l = threadIdx.x;
    __shared__ int extr[MAXLEN];
    __shared__ int red[MAXLEN];

    const int m = mask[b * MAXLEN + l];
    red[l] = m;
    __syncthreads();
    for (int s = 64; s > 0; s >>= 1) {
        if (l < s) red[l] += red[l + s];
        __syncthreads();
    }
    const int shift = red[0];                 // = sum(mask[b,:])

    const int prev = (l == 0) ? 1 : psg[b * MAXLEN + l - 1];
    const int fm   = 1 - mask[b * MAXLEN + (MAXLEN - 1 - l)];
    extr[l] = fm * prev;
    __syncthreads();

    const int pos = (l - shift + MAXLEN) & (MAXLEN - 1);   // (l-shift) mod 128
    const int tr  = extr[pos];
    trunc_out[b * MAXLEN + l] = tr;

    red[l] = (tr != 0) ? l : MAXLEN;
    __syncthreads();
    for (int s = 64; s > 0; s >>= 1) {
        if (l < s) red[l] = min(red[l], red[l + s]);
        __syncthreads();
    }
    if (l == 0) firstnz_out[b] = red[0];      // flag[l] = (l >= firstnz)
}

// ---------------------------------------------------------------------------
// Kernel 3: out[b,l,:] = (mask ? W[row_idx] : 0) + (flag ? W[trunc] : 0)
// One block (192 threads = 768/4 float4) per (b,l).
// ---------------------------------------------------------------------------
__global__ __launch_bounds__(192) void gather_add(
        const float* __restrict__ W,
        const int* __restrict__ mask,
        const int* __restrict__ row_idx,
        const int* __restrict__ trunc,
        const int* __restrict__ firstnz,
        float* __restrict__ out) {
    const int blk = blockIdx.x;               // b*128 + l
    const int b   = blk >> 7;
    const int l   = blk & (MAXLEN - 1);
    const int tid = threadIdx.x;

    const int m    = mask[blk];
    const int r1   = row_idx[blk];
    const int tr   = trunc[blk];
    const bool flg = (l >= firstnz[b]);

    const float4* __restrict__ W4 = (const float4*)W;
    float4 acc = make_float4(0.f, 0.f, 0.f, 0.f);
    if (m) {
        float4 w = W4[(size_t)r1 * (EMBED / 4) + tid];
        acc.x += w.x; acc.y += w.y; acc.z += w.z; acc.w += w.w;
    }
    if (flg) {
        float4 w = W4[(size_t)tr * (EMBED / 4) + tid];
        acc.x += w.x; acc.y += w.y; acc.z += w.z; acc.w += w.w;
    }
    ((float4*)out)[(size_t)blk * (EMBED / 4) + tid] = acc;
}

// ---------------------------------------------------------------------------
extern "C" void kernel_launch(void* const* d_in, const int* in_sizes, int n_in,
                              void* d_out, int out_size, void* d_ws, size_t ws_size,
                              hipStream_t stream) {
    const float* logits = (const float*)d_in[0];
    const int*   mask   = (const int*)  d_in[1];
    const int*   psg    = (const int*)  d_in[2];
    const float* W      = (const float*)d_in[3];
    const float* gumbel = (const float*)d_in[4];
    float* out = (float*)d_out;

    int* ws_row   = (int*)d_ws;               // [NROWS]
    int* ws_trunc = ws_row + NROWS;           // [NROWS]
    int* ws_fnz   = ws_trunc + NROWS;         // [BATCH]

    argmax_rows<<<NROWS, 256, 0, stream>>>(logits, gumbel, ws_row);
    prep_psg<<<BATCH, MAXLEN, 0, stream>>>(mask, psg, ws_trunc, ws_fnz);
    gather_add<<<NROWS, EMBED / 4, 0, stream>>>(W, mask, ws_row, ws_trunc, ws_fnz, out);
}